// Round 11
// baseline (120.342 us; speedup 1.0000x reference)
//
#include <hip/hip_runtime.h>

// StableContrastiveLoss on MI355X (gfx950).  B=4096, D=512, C=10, T=0.07.
// Round 11: BARRIER-FREE K-loop. R10 falsified the fence-only story: fence-
// free 128x128 DMA = 47us measured; R9's 64x64 DMA ~30us; both >>8us L2
// floor. Fitted model: per-K-iter __syncthreads+vmcnt(0) drain costs
// ~600-1100 cyc/block-iter (all waves park while DMA round-trips L2).
// Fix: direct-global MFMA fragment loads (no LDS staging, no per-iter
// barriers, compiler per-use vmcnt) at 2080 blocks / 64x64 tiles / 2 waves
// (R9 blocking: acc[2][4]) = 16 free-running waves/CU, ~96KB loads in
// flight/CU. Atomic-free P-store epilogue (R8). NEVER per-block
// __threadfence (R6: ~40us/528 blocks).
// ws: F_bf16[4096*512] | cls[4096] | P_all[64*64*64] | P_pos[...] | totals[2]

#define B_ROWS 4096
#define D_DIM  512
#define C_CLS  10
#define NT     64                     // 4096/64 tiles per dim
#define NTILES (NT * (NT + 1) / 2)    // 2080 upper-triangle tiles

typedef __bf16 bf16x8 __attribute__((ext_vector_type(8)));
typedef float  f32x4  __attribute__((ext_vector_type(4)));

// ---------------- Kernel 1: normalize rows + class extract ----------------
__global__ __launch_bounds__(256) void prep_kernel(
    const float* __restrict__ feats, const float* __restrict__ labels,
    __bf16* __restrict__ F, int* __restrict__ cls,
    float* __restrict__ totals) {
  const int w = threadIdx.x >> 6, lane = threadIdx.x & 63;
  const int row = blockIdx.x * 4 + w;   // one wave per row
  const float* fr = feats + (size_t)row * D_DIM;
  float4 v0 = ((const float4*)fr)[2 * lane];
  float4 v1 = ((const float4*)fr)[2 * lane + 1];
  float ss = v0.x*v0.x + v0.y*v0.y + v0.z*v0.z + v0.w*v0.w
           + v1.x*v1.x + v1.y*v1.y + v1.z*v1.z + v1.w*v1.w;
  #pragma unroll
  for (int m = 1; m < 64; m <<= 1) ss += __shfl_xor(ss, m, 64);
  float inv = 1.0f / sqrtf(ss);

  bf16x8 o;
  o[0] = (__bf16)(v0.x * inv); o[1] = (__bf16)(v0.y * inv);
  o[2] = (__bf16)(v0.z * inv); o[3] = (__bf16)(v0.w * inv);
  o[4] = (__bf16)(v1.x * inv); o[5] = (__bf16)(v1.y * inv);
  o[6] = (__bf16)(v1.z * inv); o[7] = (__bf16)(v1.w * inv);
  *(bf16x8*)(F + (size_t)row * D_DIM + 8 * lane) = o;

  float lv = (lane < C_CLS) ? labels[(size_t)row * C_CLS + lane] : 0.f;
  unsigned long long m = __ballot(lv > 0.5f);
  if (lane == 0) cls[row] = (int)(__ffsll((long long)m) - 1);
  if (blockIdx.x == 0 && threadIdx.x == 0) { totals[0] = 0.f; totals[1] = 0.f; }
}

// ---- Kernel 2: symmetric 64x64 sim, direct-global fragments, no barriers --
// 2 waves; wave w computes rows 32w..32w+31 x all 64 cols (acc[2][4]).
// A-operand layout (m89/m91): m = lane&15, k = (lane>>4)*8 + j. NT symmetry:
// B fragment = same pattern on rows j. All K-offsets (k0*2 <= 960B) fit the
// 13-bit immediate -> K-loop is pure global_load_dwordx4 + MFMA, ZERO
// barriers until the epilogue. Partials stored exactly once:
// tile(bi,bj) -> P[bi][bj][*] rows; P[bj][bi][*] cols (offdiag).
__global__ __launch_bounds__(128) void sim_kernel(
    const __bf16* __restrict__ F, const int* __restrict__ cls,
    float* __restrict__ P_all, float* __restrict__ P_pos) {
  __shared__ int clsA[64], clsB[64];
  __shared__ float g_row_all[64], g_row_pos[64];
  __shared__ float g_col_all[64], g_col_pos[64];

  // triangular tile decode (block-uniform scalar loop, <=64 iters)
  int rem = blockIdx.x, bi = 0, rowlen = NT;
  while (rem >= rowlen) { rem -= rowlen; ++bi; --rowlen; }
  const int bj = bi + rem;
  const int i0 = bi * 64, j0 = bj * 64;
  const bool offdiag = (bi != bj);

  const int t = threadIdx.x;       // 128 threads = 2 waves
  const int w = t >> 6;            // wave 0/1 -> rows 32w..32w+31
  const int lane = t & 63;
  const int q = lane >> 4;         // quad
  const int cl = lane & 15;

  if (t < 64) { clsA[t] = cls[i0 + t]; g_col_all[t] = 0.f; g_col_pos[t] = 0.f; }
  else        clsB[t - 64] = cls[j0 + t - 64];

  f32x4 acc[2][4];
  #pragma unroll
  for (int ri = 0; ri < 2; ++ri)
    #pragma unroll
    for (int c = 0; c < 4; ++c) acc[ri][c] = (f32x4){0.f, 0.f, 0.f, 0.f};

  // fragment base pointers (lane-resolved); K advances via immediate offset
  const __bf16* pa[2];
  const __bf16* pb[4];
  #pragma unroll
  for (int ri = 0; ri < 2; ++ri)
    pa[ri] = F + (size_t)(i0 + 32 * w + 16 * ri + cl) * D_DIM + q * 8;
  #pragma unroll
  for (int c = 0; c < 4; ++c)
    pb[c] = F + (size_t)(j0 + 16 * c + cl) * D_DIM + q * 8;

  #pragma unroll 4
  for (int k0 = 0; k0 < D_DIM; k0 += 32) {
    bf16x8 af[2], bfr[4];
    #pragma unroll
    for (int ri = 0; ri < 2; ++ri) af[ri] = *(const bf16x8*)(pa[ri] + k0);
    #pragma unroll
    for (int c = 0; c < 4; ++c)    bfr[c] = *(const bf16x8*)(pb[c] + k0);
    #pragma unroll
    for (int ri = 0; ri < 2; ++ri)
      #pragma unroll
      for (int c = 0; c < 4; ++c)
        acc[ri][c] = __builtin_amdgcn_mfma_f32_16x16x32_bf16(
            af[ri], bfr[c], acc[ri][c], 0, 0, 0);
  }

  __syncthreads();   // first barrier: clsA/clsB + g_col init visible

  // Epilogue. D layout (m89/m91): col = lane&15, row = (lane>>4)*4 + reg.
  const float invT = 1.0f / 0.07f;
  float cs_all[4] = {0.f, 0.f, 0.f, 0.f};
  float cs_pos[4] = {0.f, 0.f, 0.f, 0.f};

  #pragma unroll
  for (int ri = 0; ri < 2; ++ri) {
    float sum_all[4] = {0.f, 0.f, 0.f, 0.f};
    float sum_pos[4] = {0.f, 0.f, 0.f, 0.f};
    #pragma unroll
    for (int c = 0; c < 4; ++c) {
      const int jloc = 16*c + cl;
      const int gj = j0 + jloc;
      const int cj = clsB[jloc];
      #pragma unroll
      for (int r = 0; r < 4; ++r) {
        const int iloc = 32*w + 16*ri + q*4 + r;
        const int gi = i0 + iloc;
        float s = acc[ri][c][r] * invT;
        s = fminf(fmaxf(s, -20.f), 20.f);
        const bool diag = (gi == gj);
        float e = diag ? 0.f : __expf(s);
        sum_all[r] += e;
        cs_all[c] += e;
        if (!diag && cj == clsA[iloc]) { sum_pos[r] += e; cs_pos[c] += e; }
      }
    }
    // row sums -> LDS (each row written exactly once: lanes cl==0)
    #pragma unroll
    for (int r = 0; r < 4; ++r) {
      float sa = sum_all[r], sp = sum_pos[r];
      #pragma unroll
      for (int m = 1; m < 16; m <<= 1) {
        sa += __shfl_xor(sa, m, 64);
        sp += __shfl_xor(sp, m, 64);
      }
      if (cl == 0) {
        const int rloc = 32*w + 16*ri + q*4 + r;
        g_row_all[rloc] = sa;
        g_row_pos[rloc] = sp;
      }
    }
  }

  // col sums: reduce across quads, then LDS-scope atomic combine of 2 waves
  if (offdiag) {
    #pragma unroll
    for (int c = 0; c < 4; ++c) {
      float sa = cs_all[c], sp = cs_pos[c];
      sa += __shfl_xor(sa, 16, 64); sa += __shfl_xor(sa, 32, 64);
      sp += __shfl_xor(sp, 16, 64); sp += __shfl_xor(sp, 32, 64);
      if (q == 0) {
        atomicAdd(&g_col_all[16*c + cl], sa);
        atomicAdd(&g_col_pos[16*c + cl], sp);
      }
    }
  }
  __syncthreads();

  // store phase: coalesced 256B stores, exactly-once slot coverage
  if (w == 0) {
    const size_t base_row = ((size_t)bi * 64 + bj) * 64;
    P_all[base_row + lane] = g_row_all[lane];
    P_pos[base_row + lane] = g_row_pos[lane];
  } else if (offdiag) {
    const size_t base_col = ((size_t)bj * 64 + bi) * 64;
    P_all[base_col + lane] = g_col_all[lane];
    P_pos[base_col + lane] = g_col_pos[lane];
  }
}

// ---- Kernel 3: per-strip reduction (64 blocks), tiny atomics to totals ----
__global__ __launch_bounds__(256) void finalize_kernel(
    const float* __restrict__ P_all, const float* __restrict__ P_pos,
    float* __restrict__ totals) {
  __shared__ float Sall[4096], Spos[4096];   // 32 KB
  const int s = blockIdx.x;
  const int t = threadIdx.x;
  for (int i = t; i < 4096; i += 256) {
    Sall[i] = P_all[(size_t)s * 4096 + i];   // coalesced
    Spos[i] = P_pos[(size_t)s * 4096 + i];
  }
  __syncthreads();
  if (t < 64) {   // wave 0: row r = t of this strip
    float a = 0.f, p = 0.f;
    #pragma unroll 8
    for (int k = 0; k < 64; ++k) {   // column sum: 2-way bank alias (free)
      a += Sall[k * 64 + t];
      p += Spos[k * 64 + t];
    }
    float loss = 0.f, cnt = 0.f;
    if (p > 0.f) {                   // valid iff >=1 positive
      loss = -logf(p / (a + 1e-8f) + 1e-8f);
      cnt = 1.f;
    }
    #pragma unroll
    for (int m = 1; m < 64; m <<= 1) {
      loss += __shfl_xor(loss, m, 64);
      cnt  += __shfl_xor(cnt, m, 64);
    }
    if (t == 0) {                    // 128 atomics total across the grid
      atomicAdd(&totals[0], loss);
      atomicAdd(&totals[1], cnt);
    }
  }
}

// ---------------- Kernel 4: scalar division ----------------
__global__ void div_kernel(const float* __restrict__ totals,
                           float* __restrict__ out) {
  out[0] = (totals[1] > 0.f) ? (totals[0] / totals[1]) : 0.f;
}

extern "C" void kernel_launch(void* const* d_in, const int* in_sizes, int n_in,
                              void* d_out, int out_size, void* d_ws, size_t ws_size,
                              hipStream_t stream) {
  const float* features = (const float*)d_in[0];
  const float* labels   = (const float*)d_in[1];
  float* out = (float*)d_out;

  __bf16* F      = (__bf16*)d_ws;
  int*    cls    = (int*)((char*)d_ws + (size_t)B_ROWS * D_DIM * 2);
  float*  P_all  = (float*)((char*)cls + B_ROWS * sizeof(int));
  float*  P_pos  = P_all + (size_t)NT * NT * 64;
  float*  totals = P_pos + (size_t)NT * NT * 64;

  prep_kernel<<<B_ROWS / 4, 256, 0, stream>>>(features, labels, F, cls, totals);
  sim_kernel<<<NTILES, 128, 0, stream>>>(F, cls, P_all, P_pos);
  finalize_kernel<<<NT, 256, 0, stream>>>(P_all, P_pos, totals);
  div_kernel<<<1, 1, 0, stream>>>(totals, out);
}

// Round 12
// 96.528 us; speedup vs baseline: 1.2467x; 1.2467x over previous
//
#include <hip/hip_runtime.h>

// StableContrastiveLoss on MI355X (gfx950).  B=4096, D=512, C=10, T=0.07.
// Round 12: L2-BW-bound theory (fits R1..R11: eff. L2 BW 7-12 TB/s; sim time
// ~= staging bytes / eff-BW). Cut bytes: 128x128 tiles (134 MB vs 64-tile's
// 268 MB) while keeping saturation: 8 waves/block (512 thr) -> 16 waves/CU
// at 2 blk/CU, and stage via R1-style coalesced vector loads (11.6 TB/s
// observed) rather than global_load_lds DMA (7.2). XOR chunk swizzle keeps
// writes 2-way (free) and frag reads conflict-free. Atomic-free P epilogue.
// NEVER per-block __threadfence (R6).
// ws: F_bf16[4096*512] | cls[4096] | P_all[32*32*128] | P_pos[...] | totals[2]

#define B_ROWS 4096
#define D_DIM  512
#define C_CLS  10
#define NTB    32                      // 4096/128 tile-blocks per dim
#define NTILES (NTB * (NTB + 1) / 2)   // 528 upper-triangle tiles

typedef __bf16 bf16x8 __attribute__((ext_vector_type(8)));
typedef float  f32x4  __attribute__((ext_vector_type(4)));

// ---------------- Kernel 1: normalize rows + class extract ----------------
__global__ __launch_bounds__(256) void prep_kernel(
    const float* __restrict__ feats, const float* __restrict__ labels,
    __bf16* __restrict__ F, int* __restrict__ cls,
    float* __restrict__ totals) {
  const int w = threadIdx.x >> 6, lane = threadIdx.x & 63;
  const int row = blockIdx.x * 4 + w;   // one wave per row
  const float* fr = feats + (size_t)row * D_DIM;
  float4 v0 = ((const float4*)fr)[2 * lane];
  float4 v1 = ((const float4*)fr)[2 * lane + 1];
  float ss = v0.x*v0.x + v0.y*v0.y + v0.z*v0.z + v0.w*v0.w
           + v1.x*v1.x + v1.y*v1.y + v1.z*v1.z + v1.w*v1.w;
  #pragma unroll
  for (int m = 1; m < 64; m <<= 1) ss += __shfl_xor(ss, m, 64);
  float inv = 1.0f / sqrtf(ss);

  bf16x8 o;
  o[0] = (__bf16)(v0.x * inv); o[1] = (__bf16)(v0.y * inv);
  o[2] = (__bf16)(v0.z * inv); o[3] = (__bf16)(v0.w * inv);
  o[4] = (__bf16)(v1.x * inv); o[5] = (__bf16)(v1.y * inv);
  o[6] = (__bf16)(v1.z * inv); o[7] = (__bf16)(v1.w * inv);
  *(bf16x8*)(F + (size_t)row * D_DIM + 8 * lane) = o;

  float lv = (lane < C_CLS) ? labels[(size_t)row * C_CLS + lane] : 0.f;
  unsigned long long m = __ballot(lv > 0.5f);
  if (lane == 0) cls[row] = (int)(__ffsll((long long)m) - 1);
  if (blockIdx.x == 0 && threadIdx.x == 0) { totals[0] = 0.f; totals[1] = 0.f; }
}

// --- Kernel 2: 128x128 symmetric sim, 8 waves, VALU staging, no atomics ---
// Wave (wi = w&1, wj = w>>1): rows 64wi..+63 x cols 32wj..+31, acc[4][2].
// LDS[row][c] = global 16B-chunk c^(row&7), rows unpadded (64 bf16).
// Staging: thread t -> row t/4, chunk pair (t&3)*2 (coalesced 32B/thread).
__global__ __launch_bounds__(512) void sim_kernel(
    const __bf16* __restrict__ F, const int* __restrict__ cls,
    float* __restrict__ P_all, float* __restrict__ P_pos) {
  __shared__ __align__(16) __bf16 Abuf[128 * 64];
  __shared__ __align__(16) __bf16 Bbuf[128 * 64];
  __shared__ int clsA[128], clsB[128];
  __shared__ float g_row_all[128], g_row_pos[128];
  __shared__ float g_col_all[128], g_col_pos[128];

  // triangular tile decode (block-uniform scalar loop, <=32 iters)
  int rem = blockIdx.x, bi = 0, rowlen = NTB;
  while (rem >= rowlen) { rem -= rowlen; ++bi; --rowlen; }
  const int bj = bi + rem;
  const int i0 = bi * 128, j0 = bj * 128;
  const bool offdiag = (bi != bj);

  const int t = threadIdx.x;       // 512 threads = 8 waves
  const int w = t >> 6, lane = t & 63;
  const int wi = w & 1, wj = w >> 1;   // 2x4 wave grid
  const int q = lane >> 4, cl = lane & 15;

  if (t < 128) { clsA[t] = cls[i0 + t]; g_row_all[t] = 0.f; g_row_pos[t] = 0.f; }
  else if (t < 256) {
    clsB[t-128] = cls[j0 + t - 128];
    g_col_all[t-128] = 0.f; g_col_pos[t-128] = 0.f;
  }

  f32x4 acc[4][2];
  #pragma unroll
  for (int ri = 0; ri < 4; ++ri)
    #pragma unroll
    for (int cj = 0; cj < 2; ++cj) acc[ri][cj] = (f32x4){0.f, 0.f, 0.f, 0.f};

  // staging role: thread t -> row t>>2, chunks c0=(t&3)*2, c0+1 (16B each)
  const int srow = t >> 2;
  const int c0   = (t & 3) * 2;
  const int sw0  = c0 ^ (srow & 7);        // swizzled LDS chunk for c0
  const int sw1  = (c0 + 1) ^ (srow & 7);  // and c0+1

  for (int k0 = 0; k0 < D_DIM; k0 += 64) {
    __syncthreads();  // previous iteration's readers done (covers init too)
    {
      const uint4* ga = (const uint4*)(F + (size_t)(i0 + srow) * D_DIM + k0 + c0 * 8);
      const uint4* gb = (const uint4*)(F + (size_t)(j0 + srow) * D_DIM + k0 + c0 * 8);
      uint4 a0 = ga[0], a1 = ga[1];
      uint4 b0 = gb[0], b1 = gb[1];
      *(uint4*)&Abuf[srow * 64 + sw0 * 8] = a0;
      *(uint4*)&Abuf[srow * 64 + sw1 * 8] = a1;
      *(uint4*)&Bbuf[srow * 64 + sw0 * 8] = b0;
      *(uint4*)&Bbuf[srow * 64 + sw1 * 8] = b1;
    }
    __syncthreads();

    #pragma unroll
    for (int kk = 0; kk < 64; kk += 32) {
      const int cc = ((kk >> 3) + q) ^ (cl & 7);   // swizzled LDS chunk
      bf16x8 af[4], bf[2];
      #pragma unroll
      for (int ri = 0; ri < 4; ++ri)
        af[ri] = *(const bf16x8*)&Abuf[(64 * wi + 16 * ri + cl) * 64 + cc * 8];
      #pragma unroll
      for (int cj = 0; cj < 2; ++cj)
        bf[cj] = *(const bf16x8*)&Bbuf[(32 * wj + 16 * cj + cl) * 64 + cc * 8];
      #pragma unroll
      for (int ri = 0; ri < 4; ++ri)
        #pragma unroll
        for (int cj = 0; cj < 2; ++cj)
          acc[ri][cj] = __builtin_amdgcn_mfma_f32_16x16x32_bf16(
              af[ri], bf[cj], acc[ri][cj], 0, 0, 0);
    }
  }

  // Epilogue. D layout (m89/m91): col = lane&15, row = (lane>>4)*4 + reg.
  const float invT = 1.0f / 0.07f;
  float cs_all[2] = {0.f, 0.f};
  float cs_pos[2] = {0.f, 0.f};

  #pragma unroll
  for (int ri = 0; ri < 4; ++ri) {
    float ra[4] = {0.f, 0.f, 0.f, 0.f};
    float rp[4] = {0.f, 0.f, 0.f, 0.f};
    #pragma unroll
    for (int cj = 0; cj < 2; ++cj) {
      const int jloc = 32 * wj + 16 * cj + cl;
      const int gj = j0 + jloc;
      const int cjc = clsB[jloc];
      #pragma unroll
      for (int r = 0; r < 4; ++r) {
        const int iloc = 64 * wi + 16 * ri + q * 4 + r;
        const int gi = i0 + iloc;
        float s = acc[ri][cj][r] * invT;
        s = fminf(fmaxf(s, -20.f), 20.f);
        const bool diag = (gi == gj);
        float e = diag ? 0.f : __expf(s);
        ra[r] += e;
        cs_all[cj] += e;
        if (!diag && cjc == clsA[iloc]) { rp[r] += e; cs_pos[cj] += e; }
      }
    }
    // row partials (this wave's 32 cols) -> LDS atomic combine (4 wj waves)
    #pragma unroll
    for (int r = 0; r < 4; ++r) {
      float sa = ra[r], sp = rp[r];
      #pragma unroll
      for (int m = 1; m < 16; m <<= 1) {
        sa += __shfl_xor(sa, m, 64);
        sp += __shfl_xor(sp, m, 64);
      }
      if (cl == 0) {
        const int rloc = 64 * wi + 16 * ri + q * 4 + r;
        atomicAdd(&g_row_all[rloc], sa);   // LDS-scope, cheap
        atomicAdd(&g_row_pos[rloc], sp);
      }
    }
  }
  // col partials (this wave's 64 rows) -> LDS atomic combine (2 wi waves)
  if (offdiag) {
    #pragma unroll
    for (int cj = 0; cj < 2; ++cj) {
      float sa = cs_all[cj], sp = cs_pos[cj];
      sa += __shfl_xor(sa, 16, 64); sa += __shfl_xor(sa, 32, 64);
      sp += __shfl_xor(sp, 16, 64); sp += __shfl_xor(sp, 32, 64);
      if (q == 0) {
        const int jloc = 32 * wj + 16 * cj + cl;
        atomicAdd(&g_col_all[jloc], sa);
        atomicAdd(&g_col_pos[jloc], sp);
      }
    }
  }
  __syncthreads();

  // store phase: coalesced 512B stores, exactly-once slot coverage
  if (t < 128) {
    const size_t base_row = ((size_t)bi * NTB + bj) * 128;
    P_all[base_row + t] = g_row_all[t];
    P_pos[base_row + t] = g_row_pos[t];
  } else if (t < 256 && offdiag) {
    const size_t base_col = ((size_t)bj * NTB + bi) * 128;
    P_all[base_col + t - 128] = g_col_all[t - 128];
    P_pos[base_col + t - 128] = g_col_pos[t - 128];
  }
}

// ---- Kernel 3: per-strip reduction (32 blocks), tiny atomics to totals ----
__global__ __launch_bounds__(256) void finalize_kernel(
    const float* __restrict__ P_all, const float* __restrict__ P_pos,
    float* __restrict__ totals) {
  __shared__ float Sall[4096], Spos[4096];   // 32 slots x 128 rows
  __shared__ float redL[2], redC[2];
  const int s = blockIdx.x;
  const int t = threadIdx.x;
  for (int i = t; i < 4096; i += 256) {
    Sall[i] = P_all[(size_t)s * 4096 + i];   // coalesced
    Spos[i] = P_pos[(size_t)s * 4096 + i];
  }
  __syncthreads();
  if (t < 128) {   // waves 0,1: row r = t of this 128-row strip
    float a = 0.f, p = 0.f;
    #pragma unroll 8
    for (int k = 0; k < 32; ++k) {
      a += Sall[k * 128 + t];
      p += Spos[k * 128 + t];
    }
    float loss = 0.f, cnt = 0.f;
    if (p > 0.f) {                   // valid iff >=1 positive
      loss = -logf(p / (a + 1e-8f) + 1e-8f);
      cnt = 1.f;
    }
    #pragma unroll
    for (int m = 1; m < 64; m <<= 1) {
      loss += __shfl_xor(loss, m, 64);
      cnt  += __shfl_xor(cnt, m, 64);
    }
    if ((t & 63) == 0) { redL[t >> 6] = loss; redC[t >> 6] = cnt; }
  }
  __syncthreads();
  if (t == 0) {                      // 64 atomics total across the grid
    atomicAdd(&totals[0], redL[0] + redL[1]);
    atomicAdd(&totals[1], redC[0] + redC[1]);
  }
}

// ---------------- Kernel 4: scalar division ----------------
__global__ void div_kernel(const float* __restrict__ totals,
                           float* __restrict__ out) {
  out[0] = (totals[1] > 0.f) ? (totals[0] / totals[1]) : 0.f;
}

extern "C" void kernel_launch(void* const* d_in, const int* in_sizes, int n_in,
                              void* d_out, int out_size, void* d_ws, size_t ws_size,
                              hipStream_t stream) {
  const float* features = (const float*)d_in[0];
  const float* labels   = (const float*)d_in[1];
  float* out = (float*)d_out;

  __bf16* F      = (__bf16*)d_ws;
  int*    cls    = (int*)((char*)d_ws + (size_t)B_ROWS * D_DIM * 2);
  float*  P_all  = (float*)((char*)cls + B_ROWS * sizeof(int));
  float*  P_pos  = P_all + (size_t)NTB * NTB * 128;
  float*  totals = P_pos + (size_t)NTB * NTB * 128;

  prep_kernel<<<B_ROWS / 4, 256, 0, stream>>>(features, labels, F, cls, totals);
  sim_kernel<<<NTILES, 512, 0, stream>>>(F, cls, P_all, P_pos);
  finalize_kernel<<<NTB, 256, 0, stream>>>(P_all, P_pos, totals);
  div_kernel<<<1, 1, 0, stream>>>(totals, out);
}

// Round 13
// 84.841 us; speedup vs baseline: 1.4184x; 1.1377x over previous
//
#include <hip/hip_runtime.h>

// StableContrastiveLoss on MI355X (gfx950).  B=4096, D=512, C=10, T=0.07.
// Round 13: FP8 sim. Unified R1-R12 model: fence-free sims are global-read
// BW-bound at ~7-12 TB/s effective; time tracks staged bytes at fixed ~8
// blk/CU overlap (R12's 128-tile cut bytes but fell to 2 blk/CU latency
// regime, R10-style). So: halve bytes with fp8 e4m3 (F = 2 MB, L2-resident
// per XCD) on the UNCHANGED R9 structure (2080 blocks, 64x64 tiles, 2 waves,
// DMA staging, XOR swizzle, atomic-free P epilogue). Layout risk is nil:
// A.A^T dot products are invariant to the HW k-permutation when both
// operands use the same element convention; C/D layout is shape-determined
// (m121/m127). exp convexity bias cancels in pos/all ratio.
// NEVER per-block __threadfence (R6).
// ws: F8[4096*512 fp8] | cls[4096] | P_all[64*64*64] | P_pos[...] | totals[2]

#define B_ROWS 4096
#define D_DIM  512
#define C_CLS  10
#define NT     64                     // 4096/64 tiles per dim
#define NTILES (NT * (NT + 1) / 2)    // 2080 upper-triangle tiles

typedef float f32x4 __attribute__((ext_vector_type(4)));

// async global->LDS DMA, 16B/lane; LDS dest = wave-uniform base + lane*16
__device__ __forceinline__ void load_lds16(const void* g, void* l) {
  __builtin_amdgcn_global_load_lds(
      (const __attribute__((address_space(1))) unsigned int*)g,
      (__attribute__((address_space(3))) unsigned int*)l, 16, 0, 0);
}

// ---------------- Kernel 1: normalize rows -> fp8, class extract -----------
__global__ __launch_bounds__(256) void prep_kernel(
    const float* __restrict__ feats, const float* __restrict__ labels,
    unsigned char* __restrict__ F8, int* __restrict__ cls,
    float* __restrict__ totals) {
  const int w = threadIdx.x >> 6, lane = threadIdx.x & 63;
  const int row = blockIdx.x * 4 + w;   // one wave per row
  const float* fr = feats + (size_t)row * D_DIM;
  float4 v0 = ((const float4*)fr)[2 * lane];
  float4 v1 = ((const float4*)fr)[2 * lane + 1];
  float ss = v0.x*v0.x + v0.y*v0.y + v0.z*v0.z + v0.w*v0.w
           + v1.x*v1.x + v1.y*v1.y + v1.z*v1.z + v1.w*v1.w;
  #pragma unroll
  for (int m = 1; m < 64; m <<= 1) ss += __shfl_xor(ss, m, 64);
  float inv = 1.0f / sqrtf(ss);

  // pack 8 normalized values into 8 fp8 e4m3 (OCP on gfx950)
  int p0 = __builtin_amdgcn_cvt_pk_fp8_f32(v0.x * inv, v0.y * inv, 0, 0);
  p0     = __builtin_amdgcn_cvt_pk_fp8_f32(v0.z * inv, v0.w * inv, p0, 1);
  int p1 = __builtin_amdgcn_cvt_pk_fp8_f32(v1.x * inv, v1.y * inv, 0, 0);
  p1     = __builtin_amdgcn_cvt_pk_fp8_f32(v1.z * inv, v1.w * inv, p1, 1);
  int2 pk; pk.x = p0; pk.y = p1;
  *(int2*)(F8 + (size_t)row * D_DIM + 8 * lane) = pk;

  float lv = (lane < C_CLS) ? labels[(size_t)row * C_CLS + lane] : 0.f;
  unsigned long long m = __ballot(lv > 0.5f);
  if (lane == 0) cls[row] = (int)(__ffsll((long long)m) - 1);
  if (blockIdx.x == 0 && threadIdx.x == 0) { totals[0] = 0.f; totals[1] = 0.f; }
}

// ------- Kernel 2: symmetric 64x64 fp8 sim, 2 waves, atomic-free -----------
// LDS tile: 64 rows x 128 B (BK=128 fp8), 8 chunks of 16B per row;
// LDS[row][c] = global chunk c^(row&7)  (DMA-compatible, 2-way max reads).
// 4 staging iters; inner: 4 k-steps x acc[2][4] mfma_f32_16x16x32_fp8_fp8.
__global__ __launch_bounds__(128) void sim_kernel(
    const unsigned char* __restrict__ F8, const int* __restrict__ cls,
    float* __restrict__ P_all, float* __restrict__ P_pos) {
  __shared__ __align__(16) unsigned char Abuf[64 * 128];
  __shared__ __align__(16) unsigned char Bbuf[64 * 128];
  __shared__ int clsA[64], clsB[64];
  __shared__ float g_row_all[64], g_row_pos[64];
  __shared__ float g_col_all[64], g_col_pos[64];

  // triangular tile decode (block-uniform scalar loop, <=64 iters)
  int rem = blockIdx.x, bi = 0, rowlen = NT;
  while (rem >= rowlen) { rem -= rowlen; ++bi; --rowlen; }
  const int bj = bi + rem;
  const int i0 = bi * 64, j0 = bj * 64;
  const bool offdiag = (bi != bj);

  const int t = threadIdx.x;       // 128 threads = 2 waves
  const int w = t >> 6;            // wave 0/1 -> rows 32w..32w+31
  const int lane = t & 63;
  const int q = lane >> 4;         // quad
  const int cl = lane & 15;

  if (t < 64) { clsA[t] = cls[i0 + t]; g_col_all[t] = 0.f; g_col_pos[t] = 0.f; }
  else        clsB[t - 64] = cls[j0 + t - 64];

  f32x4 acc[2][4];
  #pragma unroll
  for (int ri = 0; ri < 2; ++ri)
    #pragma unroll
    for (int c = 0; c < 4; ++c) acc[ri][c] = (f32x4){0.f, 0.f, 0.f, 0.f};

  // DMA roles: lane L -> subrow L/8, LDS chunk L%8, global chunk (L%8)^(L/8)
  const int srow = lane >> 3;
  const int sg   = (lane & 7) ^ srow;

  for (int k0 = 0; k0 < D_DIM; k0 += 128) {   // 4 staging iters (128 fp8 = 128B)
    __syncthreads();  // previous readers done (covers cls/g_col init too)
    #pragma unroll
    for (int r = 0; r < 4; ++r) {
      const int rowbase = 32 * w + r * 8;     // wave-uniform, multiple of 8
      load_lds16(F8 + (size_t)(i0 + rowbase + srow) * D_DIM + k0 + sg * 16,
                 &Abuf[rowbase * 128]);
      load_lds16(F8 + (size_t)(j0 + rowbase + srow) * D_DIM + k0 + sg * 16,
                 &Bbuf[rowbase * 128]);
    }
    __syncthreads();  // barrier drain completes the DMA

    #pragma unroll
    for (int ks = 0; ks < 4; ++ks) {          // 4 k-steps of 32 fp8
      // frag = 8 fp8 at row-byte (ks*32 + q*8): chunk g = ks*2 + (q>>1),
      // 8B half h = q&1; swizzled LDS chunk = g ^ (row&7)
      const int g = ks * 2 + (q >> 1);
      const int h = (q & 1) * 8;
      long af[2]; long bf[4];
      #pragma unroll
      for (int ri = 0; ri < 2; ++ri) {
        const int row = 32 * w + 16 * ri + cl;
        af[ri] = *(const long*)&Abuf[row * 128 + ((g ^ (row & 7)) * 16) + h];
      }
      #pragma unroll
      for (int c = 0; c < 4; ++c) {
        const int row = 16 * c + cl;
        bf[c] = *(const long*)&Bbuf[row * 128 + ((g ^ (row & 7)) * 16) + h];
      }
      #pragma unroll
      for (int ri = 0; ri < 2; ++ri)
        #pragma unroll
        for (int c = 0; c < 4; ++c)
          acc[ri][c] = __builtin_amdgcn_mfma_f32_16x16x32_fp8_fp8(
              af[ri], bf[c], acc[ri][c], 0, 0, 0);
    }
  }

  // Epilogue. D layout (shape-determined, m89/m121): col=lane&15, row=q*4+reg.
  const float invT = 1.0f / 0.07f;
  float cs_all[4] = {0.f, 0.f, 0.f, 0.f};
  float cs_pos[4] = {0.f, 0.f, 0.f, 0.f};

  #pragma unroll
  for (int ri = 0; ri < 2; ++ri) {
    float sum_all[4] = {0.f, 0.f, 0.f, 0.f};
    float sum_pos[4] = {0.f, 0.f, 0.f, 0.f};
    #pragma unroll
    for (int c = 0; c < 4; ++c) {
      const int jloc = 16*c + cl;
      const int gj = j0 + jloc;
      const int cj = clsB[jloc];
      #pragma unroll
      for (int r = 0; r < 4; ++r) {
        const int iloc = 32*w + 16*ri + q*4 + r;
        const int gi = i0 + iloc;
        float s = acc[ri][c][r] * invT;
        s = fminf(fmaxf(s, -20.f), 20.f);
        const bool diag = (gi == gj);
        float e = diag ? 0.f : __expf(s);
        sum_all[r] += e;
        cs_all[c] += e;
        if (!diag && cj == clsA[iloc]) { sum_pos[r] += e; cs_pos[c] += e; }
      }
    }
    // row sums -> LDS (each row written exactly once: lanes cl==0)
    #pragma unroll
    for (int r = 0; r < 4; ++r) {
      float sa = sum_all[r], sp = sum_pos[r];
      #pragma unroll
      for (int m = 1; m < 16; m <<= 1) {
        sa += __shfl_xor(sa, m, 64);
        sp += __shfl_xor(sp, m, 64);
      }
      if (cl == 0) {
        const int rloc = 32*w + 16*ri + q*4 + r;
        g_row_all[rloc] = sa;
        g_row_pos[rloc] = sp;
      }
    }
  }

  // col sums: reduce across quads, then LDS-scope atomic combine of 2 waves
  if (offdiag) {
    #pragma unroll
    for (int c = 0; c < 4; ++c) {
      float sa = cs_all[c], sp = cs_pos[c];
      sa += __shfl_xor(sa, 16, 64); sa += __shfl_xor(sa, 32, 64);
      sp += __shfl_xor(sp, 16, 64); sp += __shfl_xor(sp, 32, 64);
      if (q == 0) {
        atomicAdd(&g_col_all[16*c + cl], sa);
        atomicAdd(&g_col_pos[16*c + cl], sp);
      }
    }
  }
  __syncthreads();

  // store phase: coalesced 256B stores, exactly-once slot coverage
  if (w == 0) {
    const size_t base_row = ((size_t)bi * 64 + bj) * 64;
    P_all[base_row + lane] = g_row_all[lane];
    P_pos[base_row + lane] = g_row_pos[lane];
  } else if (offdiag) {
    const size_t base_col = ((size_t)bj * 64 + bi) * 64;
    P_all[base_col + lane] = g_col_all[lane];
    P_pos[base_col + lane] = g_col_pos[lane];
  }
}

// ---- Kernel 3: per-strip reduction (64 blocks), tiny atomics to totals ----
__global__ __launch_bounds__(256) void finalize_kernel(
    const float* __restrict__ P_all, const float* __restrict__ P_pos,
    float* __restrict__ totals) {
  __shared__ float Sall[4096], Spos[4096];   // 32 KB
  const int s = blockIdx.x;
  const int t = threadIdx.x;
  for (int i = t; i < 4096; i += 256) {
    Sall[i] = P_all[(size_t)s * 4096 + i];   // coalesced
    Spos[i] = P_pos[(size_t)s * 4096 + i];
  }
  __syncthreads();
  if (t < 64) {   // wave 0: row r = t of this strip
    float a = 0.f, p = 0.f;
    #pragma unroll 8
    for (int k = 0; k < 64; ++k) {   // column sum: 2-way bank alias (free)
      a += Sall[k * 64 + t];
      p += Spos[k * 64 + t];
    }
    float loss = 0.f, cnt = 0.f;
    if (p > 0.f) {                   // valid iff >=1 positive
      loss = -logf(p / (a + 1e-8f) + 1e-8f);
      cnt = 1.f;
    }
    #pragma unroll
    for (int m = 1; m < 64; m <<= 1) {
      loss += __shfl_xor(loss, m, 64);
      cnt  += __shfl_xor(cnt, m, 64);
    }
    if (t == 0) {                    // 128 atomics total across the grid
      atomicAdd(&totals[0], loss);
      atomicAdd(&totals[1], cnt);
    }
  }
}

// ---------------- Kernel 4: scalar division ----------------
__global__ void div_kernel(const float* __restrict__ totals,
                           float* __restrict__ out) {
  out[0] = (totals[1] > 0.f) ? (totals[0] / totals[1]) : 0.f;
}

extern "C" void kernel_launch(void* const* d_in, const int* in_sizes, int n_in,
                              void* d_out, int out_size, void* d_ws, size_t ws_size,
                              hipStream_t stream) {
  const float* features = (const float*)d_in[0];
  const float* labels   = (const float*)d_in[1];
  float* out = (float*)d_out;

  unsigned char* F8     = (unsigned char*)d_ws;
  int*    cls    = (int*)((char*)d_ws + (size_t)B_ROWS * D_DIM);
  float*  P_all  = (float*)((char*)cls + B_ROWS * sizeof(int));
  float*  P_pos  = P_all + (size_t)NT * NT * 64;
  float*  totals = P_pos + (size_t)NT * NT * 64;

  prep_kernel<<<B_ROWS / 4, 256, 0, stream>>>(features, labels, F8, cls, totals);
  sim_kernel<<<NTILES, 128, 0, stream>>>(F8, cls, P_all, P_pos);
  finalize_kernel<<<NT, 256, 0, stream>>>(P_all, P_pos, totals);
  div_kernel<<<1, 1, 0, stream>>>(totals, out);
}